// Round 7
// baseline (4495.726 us; speedup 1.0000x reference)
//
#include <hip/hip_runtime.h>

#define NUM_LAYERS 1000
#define DIM 10
#define STRIDE 112           // floats per affine slot (10x11 = 110, padded to 112)
#define LPB 16               // layers per chunk
#define NCHUNK 63            // ceil(1000/16)
#define WQ4 320              // float4 per wave-tile (64 lanes * 5)
#define GRID 1536            // 6 blocks/CU; capacity is 7/CU at ~22KB LDS -> all resident, no deadlock
#define NWAVES (GRID * 4)

// Affine stored col-major in a slot: slot[j*10 + r] = M[r][j] for j<10,
// slot[100 + r] = c[r]. Compose dst = g(f(.)): col_j(dst) = M_g * col_j(f)
// (+ c_g when j==10). Lane j (0..10) owns column j.
__device__ inline void compose_one(const float* __restrict__ src,
                                   float* __restrict__ dst,
                                   int c, int lane) {
    const float* F = src + (size_t)(2 * c) * STRIDE;
    const float* G = src + (size_t)(2 * c + 1) * STRIDE;
    float colf[DIM], o[DIM];
    #pragma unroll
    for (int r = 0; r < DIM; ++r) colf[r] = F[lane * DIM + r];
    #pragma unroll
    for (int r = 0; r < DIM; ++r) {
        float acc = (lane == DIM) ? G[100 + r] : 0.f;
        #pragma unroll
        for (int k = 0; k < DIM; ++k)
            acc += G[k * DIM + r] * colf[k];
        o[r] = acc;
    }
    float* D = dst + (size_t)c * STRIDE;
    #pragma unroll
    for (int r = 0; r < DIM; ++r) D[lane * DIM + r] = o[r];
}

// LDS union: compose phase / fold phase / apply phase never overlap in time
// within a block (separated by __syncthreads in uniform control flow).
union SmemU {
    float4 ap[4][WQ4];                                   // 20480 B  apply staging
    struct { float in[32 * STRIDE]; float out[16 * STRIDE]; } fold;  // 21504 B
    struct { float a[LPB * STRIDE]; float b[(LPB / 2) * STRIDE]; } p1; // 10752 B
};

// ---------------------------------------------------------------------------
// ONE kernel: compose (63 blocks) -> last-block tree fold -> flag -> apply.
// Grid co-residency guaranteed (1536 < 7/CU capacity), so the flag spin is
// deadlock-free regardless of dispatch order. Cross-XCD data handoff uses
// __threadfence + device-scope atomics (round-1-verified pattern).
// ---------------------------------------------------------------------------
__global__ __launch_bounds__(256, 6) void fused_all(const float* __restrict__ Ws,
                                                    const float* __restrict__ bs,
                                                    const float* __restrict__ x,
                                                    float* __restrict__ out,
                                                    float* __restrict__ ws_chunks,
                                                    float* __restrict__ aff,
                                                    unsigned int* __restrict__ cnt,
                                                    unsigned int* __restrict__ flag,
                                                    int nq4, int nwt) {
    __shared__ SmemU u;
    __shared__ float sA[STRIDE];       // broadcast final affine for apply
    __shared__ unsigned int sbc;       // block-uniform broadcasts
    const int tid  = threadIdx.x;
    const int w    = tid >> 6, lane = tid & 63;
    const int bid  = blockIdx.x;

    // ================= phase 1: chunk compose (blocks 0..62) =================
    if (bid < NCHUNK) {
        for (int e = tid; e < LPB * 100; e += 256) {
            int ll = e / 100, rem = e % 100;      // rem = r*10 + k
            int r = rem / 10, k = rem % 10;
            int l = bid * LPB + ll;
            float v = (l < NUM_LAYERS) ? Ws[(size_t)l * 100 + rem]
                                       : (r == k ? 1.f : 0.f);
            u.p1.a[ll * STRIDE + k * DIM + r] = v;
        }
        for (int e = tid; e < LPB * DIM; e += 256) {
            int ll = e / DIM, r = e % DIM;
            int l = bid * LPB + ll;
            float v = (l < NUM_LAYERS) ? bs[(size_t)l * DIM + r] : 0.f;
            u.p1.a[ll * STRIDE + 100 + r] = v;
        }

        {   // 4-level tree: 16 -> 8 -> 4 -> 2 -> 1 (4 waves, c += 4)
            const float* src = u.p1.a;
            float* dst = u.p1.b;
            for (int n = LPB / 2; n >= 1; n >>= 1) {
                __syncthreads();
                if (lane <= DIM)
                    for (int c = w; c < n; c += 4) compose_one(src, dst, c, lane);
                const float* t = dst; dst = (float*)src; src = t;
            }
            __syncthreads();               // even #levels -> result in u.p1.a == src
            if (tid < 110) ws_chunks[(size_t)bid * STRIDE + tid] = src[tid];
        }
        __threadfence();                   // release chunk stores to agent scope
        __syncthreads();
        if (tid == 0) sbc = atomicAdd(cnt, 1u);
        __syncthreads();

        // ============== last-arriving block: fold 63 chunks ==============
        if (sbc == NCHUNK - 1) {
            __threadfence();               // acquire side
            // stage A: chunks 0..31 -> fold.in
            for (int e = tid; e < 32 * STRIDE; e += 256) {
                int pos = e % STRIDE;
                u.fold.in[e] = (pos < 110)
                    ? __hip_atomic_load(&ws_chunks[e], __ATOMIC_RELAXED,
                                        __HIP_MEMORY_SCOPE_AGENT)
                    : 0.f;
            }
            const float* src = u.fold.in;
            float* dst = u.fold.out;
            for (int n = 16; n >= 1; n >>= 1) {   // 32 -> 1 (5 levels)
                __syncthreads();
                if (lane <= DIM)
                    for (int c = w; c < n; c += 4) compose_one(src, dst, c, lane);
                const float* t = dst; dst = (float*)src; src = t;
            }
            __syncthreads();               // odd #levels -> result in fold.out == src
            // stage B: slot 0 = P0, slots 1..31 = chunks 32..62
            if (tid < STRIDE) u.fold.in[tid] = src[tid];   // in/out disjoint
            for (int e = STRIDE + tid; e < 32 * STRIDE; e += 256) {
                int ch = e / STRIDE, pos = e % STRIDE;     // ch = 1..31
                u.fold.in[e] = (pos < 110)
                    ? __hip_atomic_load(&ws_chunks[(size_t)(NCHUNK - 32 + ch) * STRIDE + pos],
                                        __ATOMIC_RELAXED, __HIP_MEMORY_SCOPE_AGENT)
                    : 0.f;
            }
            src = u.fold.in; dst = u.fold.out;
            for (int n = 16; n >= 1; n >>= 1) {   // 32 -> 1 again
                __syncthreads();
                if (lane <= DIM)
                    for (int c = w; c < n; c += 4) compose_one(src, dst, c, lane);
                const float* t = dst; dst = (float*)src; src = t;
            }
            __syncthreads();               // result in fold.out == src, col-major
            if (tid < 110) {               // transpose M on write (row-major out)
                int addr = (tid < 100) ? ((tid % 10) * DIM + tid / 10) : tid;
                __hip_atomic_store(&aff[addr], src[tid], __ATOMIC_RELAXED,
                                   __HIP_MEMORY_SCOPE_AGENT);
            }
            __threadfence();
            __syncthreads();
            if (tid == 0)
                __hip_atomic_store(flag, 1u, __ATOMIC_RELEASE,
                                   __HIP_MEMORY_SCOPE_AGENT);
        }
    }

    // ======================= barrier: wait for affine =======================
    __syncthreads();
    if (tid == 0) {
        while (__hip_atomic_load(flag, __ATOMIC_ACQUIRE,
                                 __HIP_MEMORY_SCOPE_AGENT) == 0u)
            __builtin_amdgcn_s_sleep(32);
        sbc = 1u;
    }
    __syncthreads();
    if (tid < STRIDE)
        sA[tid] = (tid < 110)
            ? __hip_atomic_load(&aff[tid], __ATOMIC_RELAXED, __HIP_MEMORY_SCOPE_AGENT)
            : 0.f;
    __syncthreads();
    const float* __restrict__ s = sA;

    // ============================ phase 3: apply ============================
    // Proven round-5 body (47.8 us, 0 bank conflicts), per-wave grid-stride.
    const float4* __restrict__ xin = (const float4*)x;
    float4* __restrict__ op = (float4*)out;

    for (int wt = bid * 4 + w; wt < nwt; wt += NWAVES) {
        const int q0 = wt * WQ4;           // this wave's float4 base
        const int rem = nq4 - q0;

        float4 r0, r1, r2, r3, r4;
        if (0 * 64 + lane < rem) r0 = xin[q0 + 0 * 64 + lane];
        if (1 * 64 + lane < rem) r1 = xin[q0 + 1 * 64 + lane];
        if (2 * 64 + lane < rem) r2 = xin[q0 + 2 * 64 + lane];
        if (3 * 64 + lane < rem) r3 = xin[q0 + 3 * 64 + lane];
        if (4 * 64 + lane < rem) r4 = xin[q0 + 4 * 64 + lane];

        u.ap[w][0 * 64 + lane] = r0;
        u.ap[w][1 * 64 + lane] = r1;
        u.ap[w][2 * 64 + lane] = r2;
        u.ap[w][3 * 64 + lane] = r3;
        u.ap[w][4 * 64 + lane] = r4;

        asm volatile("s_waitcnt lgkmcnt(0)" ::: "memory");
        __builtin_amdgcn_sched_barrier(0);

        float xv[20];
        #pragma unroll
        for (int i = 0; i < 5; ++i) {
            float4 v = u.ap[w][5 * lane + i];
            xv[4*i+0] = v.x; xv[4*i+1] = v.y; xv[4*i+2] = v.z; xv[4*i+3] = v.w;
        }

        float o[20];
        #pragma unroll
        for (int rr = 0; rr < 2; ++rr)
            #pragma unroll
            for (int j = 0; j < DIM; ++j) {
                float acc = s[100 + j];
                #pragma unroll
                for (int k = 0; k < DIM; ++k)
                    acc += s[j * DIM + k] * xv[rr * DIM + k];
                o[rr * DIM + j] = acc;
            }

        #pragma unroll
        for (int i = 0; i < 5; ++i)
            u.ap[w][5 * lane + i] = make_float4(o[4*i+0], o[4*i+1], o[4*i+2], o[4*i+3]);

        asm volatile("s_waitcnt lgkmcnt(0)" ::: "memory");
        __builtin_amdgcn_sched_barrier(0);

        {
            float4 t0 = u.ap[w][0 * 64 + lane];
            float4 t1 = u.ap[w][1 * 64 + lane];
            float4 t2 = u.ap[w][2 * 64 + lane];
            float4 t3 = u.ap[w][3 * 64 + lane];
            float4 t4 = u.ap[w][4 * 64 + lane];
            if (0 * 64 + lane < rem) op[q0 + 0 * 64 + lane] = t0;
            if (1 * 64 + lane < rem) op[q0 + 1 * 64 + lane] = t1;
            if (2 * 64 + lane < rem) op[q0 + 2 * 64 + lane] = t2;
            if (3 * 64 + lane < rem) op[q0 + 3 * 64 + lane] = t3;
            if (4 * 64 + lane < rem) op[q0 + 4 * 64 + lane] = t4;
        }
    }
}

extern "C" void kernel_launch(void* const* d_in, const int* in_sizes, int n_in,
                              void* d_out, int out_size, void* d_ws, size_t ws_size,
                              hipStream_t stream) {
    const float* x  = (const float*)d_in[0];   // [BATCH, 10]
    const float* Ws = (const float*)d_in[1];   // [1000, 10, 10]
    const float* bs = (const float*)d_in[2];   // [1000, 10]
    float* out = (float*)d_out;

    float* ws_chunks = (float*)d_ws;                       // 63 * 112 floats
    float* ws_aff    = ws_chunks + NCHUNK * STRIDE;        // 112 floats
    unsigned int* ws_sync = (unsigned int*)(ws_aff + STRIDE);  // {cnt, flag}

    // zero counter+flag each replay (graph-capturable stream memset node)
    hipMemsetAsync(ws_sync, 0, 2 * sizeof(unsigned int), stream);

    const int nq4 = in_sizes[0] / 4;                       // in_sizes is in floats
    const int nwt = (nq4 + WQ4 - 1) / WQ4;                 // wave-tiles

    fused_all<<<GRID, 256, 0, stream>>>(Ws, bs, x, out, ws_chunks, ws_aff,
                                        ws_sync, ws_sync + 1, nq4, nwt);
}

// Round 8
// 176.121 us; speedup vs baseline: 25.5264x; 25.5264x over previous
//
#include <hip/hip_runtime.h>

#define NUM_LAYERS 1000
#define DIM 10
#define STRIDE 112           // floats per affine slot (10x11 = 110, padded to 112)
#define LPB 16               // layers per block in K1
#define NBLK 63              // ceil(1000/16)
#define WQ4 640              // float4 per wave (64 lanes * 10 = 4 rows/thread)
#define TILE_Q4 2560         // float4 per block (4 waves)

// Affine stored col-major in a slot: slot[j*10 + r] = M[r][j] for j<10,
// slot[100 + r] = c[r]. Compose dst = g(f(.)): col_j(dst) = M_g * col_j(f)
// (+ c_g when j==10). Lane j (0..10) owns column j.
__device__ inline void compose_one(const float* __restrict__ src,
                                   float* __restrict__ dst,
                                   int c, int lane) {
    const float* F = src + (size_t)(2 * c) * STRIDE;
    const float* G = src + (size_t)(2 * c + 1) * STRIDE;
    float colf[DIM], o[DIM];
    #pragma unroll
    for (int r = 0; r < DIM; ++r) colf[r] = F[lane * DIM + r];
    #pragma unroll
    for (int r = 0; r < DIM; ++r) {
        float acc = (lane == DIM) ? G[100 + r] : 0.f;
        #pragma unroll
        for (int k = 0; k < DIM; ++k)
            acc += G[k * DIM + r] * colf[k];
        o[r] = acc;
    }
    float* D = dst + (size_t)c * STRIDE;
    #pragma unroll
    for (int r = 0; r < DIM; ++r) D[lane * DIM + r] = o[r];
}

// ---------------------------------------------------------------------------
// K1 (proven): block b composes layers [b*16, b*16+16) via a 4-level LDS
// tree: 16 -> 8 -> 4 -> 2 -> 1. One wave per compose.
// ---------------------------------------------------------------------------
__global__ __launch_bounds__(1024) void compose16(const float* __restrict__ Ws,
                                                  const float* __restrict__ bs,
                                                  float* __restrict__ wsout) {
    __shared__ float A[LPB * STRIDE];
    __shared__ float B[(LPB / 2) * STRIDE];
    const int tid = threadIdx.x;
    const int blk = blockIdx.x;

    for (int e = tid; e < LPB * 100; e += 1024) {
        int ll = e / 100, rem = e % 100;      // rem = r*10 + k
        int r = rem / 10, k = rem % 10;
        int l = blk * LPB + ll;
        float v = (l < NUM_LAYERS) ? Ws[(size_t)l * 100 + rem]
                                   : (r == k ? 1.f : 0.f);
        A[ll * STRIDE + k * DIM + r] = v;
    }
    for (int e = tid; e < LPB * DIM; e += 1024) {
        int ll = e / DIM, r = e % DIM;
        int l = blk * LPB + ll;
        float v = (l < NUM_LAYERS) ? bs[(size_t)l * DIM + r] : 0.f;
        A[ll * STRIDE + 100 + r] = v;
    }

    const int wave = tid >> 6, lane = tid & 63;
    const float* src = A;
    float* dst = B;
    for (int n = LPB / 2; n >= 1; n >>= 1) {   // n = 8,4,2,1
        __syncthreads();
        if (wave < n && lane <= DIM) compose_one(src, dst, wave, lane);
        const float* t = dst; dst = (float*)src; src = t;
    }
    __syncthreads();
    if (tid < 110) wsout[(size_t)blk * STRIDE + tid] = A[tid];
}

// ---------------------------------------------------------------------------
// K2 (proven): one block folds the 63 chunk affines (padded to 64) via a
// 6-level tree. Writes the final affine ROW-major: aff[r*10+k] = M[r][k],
// aff[100+r] = c[r].
// ---------------------------------------------------------------------------
__global__ __launch_bounds__(1024) void compose_tree64(const float* __restrict__ wsin,
                                                       float* __restrict__ aff) {
    __shared__ float A[64 * STRIDE];
    __shared__ float B[32 * STRIDE];
    const int tid = threadIdx.x;

    for (int e = tid; e < 64 * STRIDE; e += 1024) {
        int chunk = e / STRIDE, pos = e % STRIDE;
        float v;
        if (pos >= 110)        v = 0.f;
        else if (chunk < NBLK) v = wsin[(size_t)chunk * STRIDE + pos];
        else v = (pos < 100 && (pos / 10 == pos % 10)) ? 1.f : 0.f;  // identity
        A[e] = v;
    }

    const int wave = tid >> 6, lane = tid & 63;
    const float* src = A;
    float* dst = B;
    for (int n = 32; n >= 1; n >>= 1) {        // n = 32,16,8,4,2,1
        __syncthreads();
        if (lane <= DIM)
            for (int c = wave; c < n; c += 16)
                compose_one(src, dst, c, lane);
        const float* t = dst; dst = (float*)src; src = t;
    }
    __syncthreads();
    if (tid < 110) {
        if (tid < 100) {
            int j = tid / DIM, r = tid % DIM;  // A[j*10+r] = M[r][j]
            aff[r * DIM + j] = A[tid];
        } else {
            aff[tid] = A[tid];                 // bias
        }
    }
}

// ---------------------------------------------------------------------------
// K3: out = M x + c. Barrier-free (round-5 proven base) + doubled per-wave
// memory ILP: ALL 10 loads (10 KB/wave in flight) are issued up front, then
// two sequential 5-float4 LDS/compute/store sub-phases reuse the wave's
// private 5 KB LDS region. Sub-phase B's loads ride out sub-phase A's whole
// LDS round-trip + compute; A's stores drain under B's compute. Intra-wave
// LDS ordering via lgkmcnt(0) + sched_barrier(0) (rule #18). LDS read
// stride 80 B = conflict-free (measured 0).
// ---------------------------------------------------------------------------
__global__ __launch_bounds__(256, 5) void apply_affine(const float* __restrict__ x,
                                                       const float* __restrict__ aff,
                                                       float* __restrict__ out,
                                                       int nq4) {
    __shared__ float4 lds4[4][320];            // 5 KB per wave, reused A/B
    __shared__ float4 s4[28];                  // 112 floats (110 used)
    const int tid  = threadIdx.x;
    const int w    = tid >> 6, lane = tid & 63;
    const float* __restrict__ s = (const float*)s4;

    // Redundant per-wave staging of the affine (identical values; each
    // wave's own first lgkm fence covers its copy).
    if (lane < 28) s4[lane] = ((const float4*)aff)[lane];

    const int q0 = blockIdx.x * TILE_Q4 + w * WQ4;   // this wave's float4 base
    const float4* __restrict__ xin = (const float4*)x + q0;
    float4* __restrict__ op = (float4*)out + q0;
    const int rem = nq4 - q0;                  // float4s this wave owns (<=640)

    // ---- issue ALL 10 coalesced loads up front (10 KB in flight) ----
    float4 r0, r1, r2, r3, r4, r5, r6, r7, r8, r9;
    if (0 * 64 + lane < rem) r0 = xin[0 * 64 + lane];
    if (1 * 64 + lane < rem) r1 = xin[1 * 64 + lane];
    if (2 * 64 + lane < rem) r2 = xin[2 * 64 + lane];
    if (3 * 64 + lane < rem) r3 = xin[3 * 64 + lane];
    if (4 * 64 + lane < rem) r4 = xin[4 * 64 + lane];
    if (5 * 64 + lane < rem) r5 = xin[5 * 64 + lane];
    if (6 * 64 + lane < rem) r6 = xin[6 * 64 + lane];
    if (7 * 64 + lane < rem) r7 = xin[7 * 64 + lane];
    if (8 * 64 + lane < rem) r8 = xin[8 * 64 + lane];
    if (9 * 64 + lane < rem) r9 = xin[9 * 64 + lane];

    // ======================= sub-phase A: float4 0..319 =======================
    lds4[w][0 * 64 + lane] = r0;
    lds4[w][1 * 64 + lane] = r1;
    lds4[w][2 * 64 + lane] = r2;
    lds4[w][3 * 64 + lane] = r3;
    lds4[w][4 * 64 + lane] = r4;

    asm volatile("s_waitcnt lgkmcnt(0)" ::: "memory");
    __builtin_amdgcn_sched_barrier(0);

    {
        float xv[20];
        #pragma unroll
        for (int i = 0; i < 5; ++i) {
            float4 v = lds4[w][5 * lane + i];
            xv[4*i+0] = v.x; xv[4*i+1] = v.y; xv[4*i+2] = v.z; xv[4*i+3] = v.w;
        }
        float o[20];
        #pragma unroll
        for (int rr = 0; rr < 2; ++rr)
            #pragma unroll
            for (int j = 0; j < DIM; ++j) {
                float acc = s[100 + j];
                #pragma unroll
                for (int k = 0; k < DIM; ++k)
                    acc += s[j * DIM + k] * xv[rr * DIM + k];
                o[rr * DIM + j] = acc;
            }
        #pragma unroll
        for (int i = 0; i < 5; ++i)
            lds4[w][5 * lane + i] = make_float4(o[4*i+0], o[4*i+1], o[4*i+2], o[4*i+3]);
    }

    asm volatile("s_waitcnt lgkmcnt(0)" ::: "memory");
    __builtin_amdgcn_sched_barrier(0);

    {
        float4 t0 = lds4[w][0 * 64 + lane];
        float4 t1 = lds4[w][1 * 64 + lane];
        float4 t2 = lds4[w][2 * 64 + lane];
        float4 t3 = lds4[w][3 * 64 + lane];
        float4 t4 = lds4[w][4 * 64 + lane];
        // ensure the t-reads are complete before sub-phase B overwrites LDS
        asm volatile("s_waitcnt lgkmcnt(0)" ::: "memory");
        __builtin_amdgcn_sched_barrier(0);
        if (0 * 64 + lane < rem) op[0 * 64 + lane] = t0;
        if (1 * 64 + lane < rem) op[1 * 64 + lane] = t1;
        if (2 * 64 + lane < rem) op[2 * 64 + lane] = t2;
        if (3 * 64 + lane < rem) op[3 * 64 + lane] = t3;
        if (4 * 64 + lane < rem) op[4 * 64 + lane] = t4;
    }

    // ======================= sub-phase B: float4 320..639 =====================
    lds4[w][0 * 64 + lane] = r5;
    lds4[w][1 * 64 + lane] = r6;
    lds4[w][2 * 64 + lane] = r7;
    lds4[w][3 * 64 + lane] = r8;
    lds4[w][4 * 64 + lane] = r9;

    asm volatile("s_waitcnt lgkmcnt(0)" ::: "memory");
    __builtin_amdgcn_sched_barrier(0);

    {
        float xv[20];
        #pragma unroll
        for (int i = 0; i < 5; ++i) {
            float4 v = lds4[w][5 * lane + i];
            xv[4*i+0] = v.x; xv[4*i+1] = v.y; xv[4*i+2] = v.z; xv[4*i+3] = v.w;
        }
        float o[20];
        #pragma unroll
        for (int rr = 0; rr < 2; ++rr)
            #pragma unroll
            for (int j = 0; j < DIM; ++j) {
                float acc = s[100 + j];
                #pragma unroll
                for (int k = 0; k < DIM; ++k)
                    acc += s[j * DIM + k] * xv[rr * DIM + k];
                o[rr * DIM + j] = acc;
            }
        #pragma unroll
        for (int i = 0; i < 5; ++i)
            lds4[w][5 * lane + i] = make_float4(o[4*i+0], o[4*i+1], o[4*i+2], o[4*i+3]);
    }

    asm volatile("s_waitcnt lgkmcnt(0)" ::: "memory");
    __builtin_amdgcn_sched_barrier(0);

    {
        float4 t0 = lds4[w][0 * 64 + lane];
        float4 t1 = lds4[w][1 * 64 + lane];
        float4 t2 = lds4[w][2 * 64 + lane];
        float4 t3 = lds4[w][3 * 64 + lane];
        float4 t4 = lds4[w][4 * 64 + lane];
        asm volatile("s_waitcnt lgkmcnt(0)" ::: "memory");
        __builtin_amdgcn_sched_barrier(0);
        if (5 * 64 + lane < rem) op[5 * 64 + lane] = t0;
        if (6 * 64 + lane < rem) op[6 * 64 + lane] = t1;
        if (7 * 64 + lane < rem) op[7 * 64 + lane] = t2;
        if (8 * 64 + lane < rem) op[8 * 64 + lane] = t3;
        if (9 * 64 + lane < rem) op[9 * 64 + lane] = t4;
    }
}

extern "C" void kernel_launch(void* const* d_in, const int* in_sizes, int n_in,
                              void* d_out, int out_size, void* d_ws, size_t ws_size,
                              hipStream_t stream) {
    const float* x  = (const float*)d_in[0];   // [BATCH, 10]
    const float* Ws = (const float*)d_in[1];   // [1000, 10, 10]
    const float* bs = (const float*)d_in[2];   // [1000, 10]
    float* out = (float*)d_out;

    float* ws_chunks = (float*)d_ws;                      // NBLK * STRIDE floats
    float* ws_aff    = ws_chunks + NBLK * STRIDE;         // 112 floats (16B aligned)

    compose16<<<NBLK, 1024, 0, stream>>>(Ws, bs, ws_chunks);
    compose_tree64<<<1, 1024, 0, stream>>>(ws_chunks, ws_aff);

    const int nq4 = in_sizes[0] / 4;                      // in_sizes is in floats
    const int blocks = (nq4 + TILE_Q4 - 1) / TILE_Q4;
    apply_affine<<<blocks, 256, 0, stream>>>(x, ws_aff, out, nq4);
}